// Round 1
// baseline (5466.294 us; speedup 1.0000x reference)
//
#include <hip/hip_runtime.h>

// Problem constants (from reference)
#define N_VOX 200000
#define K_OFF 27
#define P_PAIR 400000
#define C_IN 32
#define C_MID 64
#define C_OUT 32
#define PPB 128   // pairs per block (P_PAIR % PPB == 0)

// conv1: h[out_idx] += (feats[in_idx] @ W_in[k]) for valid pairs.
// Block = 256 threads = 4 waves; each wave processes one pair per iteration.
// Lane c (0..63) owns output channel c. W_in[k] (32x64 f32, 8KB) staged in LDS.
__global__ __launch_bounds__(256) void conv1_kernel(
    const float* __restrict__ feats,
    const int*   __restrict__ in_idx,
    const int*   __restrict__ out_idx,
    const float* __restrict__ mask,
    const float* __restrict__ W_in,
    float*       __restrict__ h)
{
    __shared__ float Ws[C_IN * C_MID];  // 2048 f32
    const int k = blockIdx.x;
    const float* Wk = W_in + (size_t)k * (C_IN * C_MID);
    for (int t = threadIdx.x; t < C_IN * C_MID; t += 256) Ws[t] = Wk[t];
    __syncthreads();

    const int g = threadIdx.x >> 6;   // wave id in block (0..3)
    const int c = threadIdx.x & 63;   // output channel
    const size_t base = (size_t)k * P_PAIR + (size_t)blockIdx.y * PPB;

    for (int pp = g; pp < PPB; pp += 4) {
        const size_t e = base + pp;
        if (mask[e] <= 0.5f) continue;        // wave-uniform branch
        const int vin  = in_idx[e];
        const int vout = out_idx[e];

        // gather input features: lanes 0..31 load, broadcast via shfl below
        float xv = 0.f;
        if (c < C_IN) xv = feats[(size_t)vin * C_IN + c];

        float y = 0.f;
#pragma unroll
        for (int i = 0; i < C_IN; ++i) {
            const float xi = __shfl(xv, i, 64);
            y += xi * Ws[i * C_MID + c];      // stride-1 over lanes: 2-way LDS alias (free)
        }
        atomicAdd(&h[(size_t)vout * C_MID + c], y);
    }
}

// conv2: out[out_idx] += (relu(h[in_idx]) @ W_out[k]) for valid pairs.
// Lane c: half = c>>5 selects which 32-row half of the 64-dot this lane sums;
// cout = c&31 is the output channel. Halves combined via shfl_xor(32).
__global__ __launch_bounds__(256) void conv2_kernel(
    const float* __restrict__ h,
    const int*   __restrict__ in_idx,
    const int*   __restrict__ out_idx,
    const float* __restrict__ mask,
    const float* __restrict__ W_out,
    float*       __restrict__ out)
{
    __shared__ float Ws[C_MID * C_OUT]; // 2048 f32
    const int k = blockIdx.x;
    const float* Wk = W_out + (size_t)k * (C_MID * C_OUT);
    for (int t = threadIdx.x; t < C_MID * C_OUT; t += 256) Ws[t] = Wk[t];
    __syncthreads();

    const int g    = threadIdx.x >> 6;
    const int c    = threadIdx.x & 63;
    const int cout = c & 31;
    const int j0   = (c >> 5) * 32;   // 0 or 32: which half of the K=64 dot
    const size_t base = (size_t)k * P_PAIR + (size_t)blockIdx.y * PPB;

    for (int pp = g; pp < PPB; pp += 4) {
        const size_t e = base + pp;
        if (mask[e] <= 0.5f) continue;
        const int vin  = in_idx[e];
        const int vout = out_idx[e];

        // gather + fused ReLU: lane c loads h[vin][c]
        const float xv = fmaxf(h[(size_t)vin * C_MID + c], 0.f);

        float y = 0.f;
#pragma unroll
        for (int i = 0; i < 32; ++i) {
            const float xi = __shfl(xv, j0 + i, 64);
            y += xi * Ws[(j0 + i) * C_OUT + cout]; // 2 rows x 32 lanes: 2-way alias (free)
        }
        y += __shfl_xor(y, 32, 64);               // combine the two halves
        if (j0 == 0) atomicAdd(&out[(size_t)vout * C_OUT + cout], y);
    }
}

extern "C" void kernel_launch(void* const* d_in, const int* in_sizes, int n_in,
                              void* d_out, int out_size, void* d_ws, size_t ws_size,
                              hipStream_t stream) {
    const float* feats  = (const float*)d_in[0];
    const int*   in_idx = (const int*)  d_in[1];
    const int*   out_idx= (const int*)  d_in[2];
    const float* mask   = (const float*)d_in[3];
    const float* W_in   = (const float*)d_in[4];
    const float* W_out  = (const float*)d_in[5];
    float* out = (float*)d_out;
    float* h   = (float*)d_ws;   // N_VOX * C_MID f32 = 51.2 MB

    // Accumulators must start at zero every call (harness does not re-poison).
    hipMemsetAsync(h,   0, (size_t)N_VOX * C_MID * sizeof(float), stream);
    hipMemsetAsync(out, 0, (size_t)N_VOX * C_OUT * sizeof(float), stream);

    dim3 grid(K_OFF, P_PAIR / PPB);
    conv1_kernel<<<grid, 256, 0, stream>>>(feats, in_idx, out_idx, mask, W_in, h);
    conv2_kernel<<<grid, 256, 0, stream>>>(h, in_idx, out_idx, mask, W_out, out);
}

// Round 3
// 1672.199 us; speedup vs baseline: 3.2689x; 3.2689x over previous
//
#include <hip/hip_runtime.h>

#define N_VOX 200000
#define K_OFF 27
#define P_PAIR 400000
#define C_IN 32
#define C_MID 64
#define C_OUT 32
#define PPB 320            // 4 waves x 5 tiles x 16 pairs; 400000 % 320 == 0
#define TILES_PER_WAVE 5

typedef __attribute__((ext_vector_type(8))) short short8;
typedef __attribute__((ext_vector_type(4))) float f32x4;

__device__ inline short f2bf(float f) {
    union { float f; unsigned u; } v; v.f = f;
    unsigned r = v.u + 0x7FFF + ((v.u >> 16) & 1);   // round-to-nearest-even
    return (short)(r >> 16);
}

// conv1: h[out_idx[e]] += (feats[in_idx[e]] @ W_in[k]) for mask>0.5.
// MFMA 16x16x32 bf16, M=16 pairs, K=32(C_IN), N=64(C_MID) via 4 N-tiles.
// A: lane l -> row r=l&15 (pair pbase+r), k = 8*(l>>4)+j  (j=0..7)
// B: lane l -> col r (channel nt*16+r), k = 8*(l>>4)+j    (same k-map as A)
// C/D (HW-verified): lane l, reg i -> row 4*(l>>4)+i, col l&15.
// Scatter: out_idx/mask for row m re-loaded DIRECTLY from global (no shfl).
__global__ __launch_bounds__(256) void conv1_mfma(
    const float* __restrict__ feats,
    const int*   __restrict__ in_idx,
    const int*   __restrict__ out_idx,
    const float* __restrict__ mask,
    const float* __restrict__ W_in,
    float*       __restrict__ h)
{
    const int k    = blockIdx.x;
    const int lane = threadIdx.x & 63;
    const int wave = threadIdx.x >> 6;
    const int g    = lane >> 4;
    const int r    = lane & 15;
    const size_t koff = (size_t)k * P_PAIR;

    const float* Wk = W_in + (size_t)k * (C_IN * C_MID);
    short8 bfrag[4];
#pragma unroll
    for (int nt = 0; nt < 4; ++nt) {
        short8 b;
#pragma unroll
        for (int j = 0; j < 8; ++j)
            b[j] = f2bf(Wk[(g * 8 + j) * C_MID + nt * 16 + r]);
        bfrag[nt] = b;
    }

    const int wbase = blockIdx.y * PPB + wave * (PPB / 4);
#pragma unroll 1
    for (int t = 0; t < TILES_PER_WAVE; ++t) {
        const int pbase = wbase + t * 16;
        const int pr = pbase + r;                    // this lane's A-row pair
        const bool avalid = (mask[koff + pr] > 0.5f);

        short8 a = {};                               // invalid rows -> zero
        if (avalid) {
            const f32x4* src = (const f32x4*)(feats + (size_t)in_idx[koff + pr] * C_IN + g * 8);
            f32x4 x0 = src[0], x1 = src[1];
#pragma unroll
            for (int j = 0; j < 4; ++j) { a[j] = f2bf(x0[j]); a[4 + j] = f2bf(x1[j]); }
        }

        f32x4 acc0 = {}, acc1 = {}, acc2 = {}, acc3 = {};
        acc0 = __builtin_amdgcn_mfma_f32_16x16x32_bf16(a, bfrag[0], acc0, 0, 0, 0);
        acc1 = __builtin_amdgcn_mfma_f32_16x16x32_bf16(a, bfrag[1], acc1, 0, 0, 0);
        acc2 = __builtin_amdgcn_mfma_f32_16x16x32_bf16(a, bfrag[2], acc2, 0, 0, 0);
        acc3 = __builtin_amdgcn_mfma_f32_16x16x32_bf16(a, bfrag[3], acc3, 0, 0, 0);

        // Scatter rows m = 4g+i (this lane's C/D rows), ground-truth indices.
#pragma unroll
        for (int i = 0; i < 4; ++i) {
            const int m = g * 4 + i;
            if (mask[koff + pbase + m] > 0.5f) {
                const int vout = out_idx[koff + pbase + m];
                float* hp = h + (size_t)vout * C_MID + r;
                atomicAdd(hp +  0, acc0[i]);
                atomicAdd(hp + 16, acc1[i]);
                atomicAdd(hp + 32, acc2[i]);
                atomicAdd(hp + 48, acc3[i]);
            }
        }
    }
}

// conv2: out[out_idx[e]] += (relu(h[in_idx[e]]) @ W_out[k]); K=64 -> 2 k-steps.
__global__ __launch_bounds__(256) void conv2_mfma(
    const float* __restrict__ h,
    const int*   __restrict__ in_idx,
    const int*   __restrict__ out_idx,
    const float* __restrict__ mask,
    const float* __restrict__ W_out,
    float*       __restrict__ out)
{
    const int k    = blockIdx.x;
    const int lane = threadIdx.x & 63;
    const int wave = threadIdx.x >> 6;
    const int g    = lane >> 4;
    const int r    = lane & 15;
    const size_t koff = (size_t)k * P_PAIR;

    const float* Wk = W_out + (size_t)k * (C_MID * C_OUT);
    short8 bfrag[2][2];   // [n-tile][k-step]
#pragma unroll
    for (int nt = 0; nt < 2; ++nt)
#pragma unroll
        for (int ks = 0; ks < 2; ++ks) {
            short8 b;
#pragma unroll
            for (int j = 0; j < 8; ++j)
                b[j] = f2bf(Wk[(ks * 32 + g * 8 + j) * C_OUT + nt * 16 + r]);
            bfrag[nt][ks] = b;
        }

    const int wbase = blockIdx.y * PPB + wave * (PPB / 4);
#pragma unroll 1
    for (int t = 0; t < TILES_PER_WAVE; ++t) {
        const int pbase = wbase + t * 16;
        const int pr = pbase + r;
        const bool avalid = (mask[koff + pr] > 0.5f);

        short8 a0 = {}, a1 = {};
        if (avalid) {
            const f32x4* src = (const f32x4*)(h + (size_t)in_idx[koff + pr] * C_MID + g * 8);
            f32x4 x0 = src[0], x1 = src[1];          // k-step 0: ch g*8 .. g*8+7
            f32x4 y0 = src[8], y1 = src[9];          // k-step 1: ch 32+g*8 ..
#pragma unroll
            for (int j = 0; j < 4; ++j) {
                a0[j]     = f2bf(fmaxf(x0[j], 0.f));
                a0[4 + j] = f2bf(fmaxf(x1[j], 0.f));
                a1[j]     = f2bf(fmaxf(y0[j], 0.f));
                a1[4 + j] = f2bf(fmaxf(y1[j], 0.f));
            }
        }

        f32x4 acc0 = {}, acc1 = {};
        acc0 = __builtin_amdgcn_mfma_f32_16x16x32_bf16(a0, bfrag[0][0], acc0, 0, 0, 0);
        acc0 = __builtin_amdgcn_mfma_f32_16x16x32_bf16(a1, bfrag[0][1], acc0, 0, 0, 0);
        acc1 = __builtin_amdgcn_mfma_f32_16x16x32_bf16(a0, bfrag[1][0], acc1, 0, 0, 0);
        acc1 = __builtin_amdgcn_mfma_f32_16x16x32_bf16(a1, bfrag[1][1], acc1, 0, 0, 0);

#pragma unroll
        for (int i = 0; i < 4; ++i) {
            const int m = g * 4 + i;
            if (mask[koff + pbase + m] > 0.5f) {
                const int vout = out_idx[koff + pbase + m];
                float* op = out + (size_t)vout * C_OUT + r;
                atomicAdd(op +  0, acc0[i]);
                atomicAdd(op + 16, acc1[i]);
            }
        }
    }
}

extern "C" void kernel_launch(void* const* d_in, const int* in_sizes, int n_in,
                              void* d_out, int out_size, void* d_ws, size_t ws_size,
                              hipStream_t stream) {
    const float* feats   = (const float*)d_in[0];
    const int*   in_idx  = (const int*)  d_in[1];
    const int*   out_idx = (const int*)  d_in[2];
    const float* mask    = (const float*)d_in[3];
    const float* W_in    = (const float*)d_in[4];
    const float* W_out   = (const float*)d_in[5];
    float* out = (float*)d_out;
    float* h   = (float*)d_ws;   // N_VOX * C_MID f32 = 51.2 MB

    hipMemsetAsync(h,   0, (size_t)N_VOX * C_MID * sizeof(float), stream);
    hipMemsetAsync(out, 0, (size_t)N_VOX * C_OUT * sizeof(float), stream);

    dim3 grid(K_OFF, P_PAIR / PPB);   // (27, 1250)
    conv1_mfma<<<grid, 256, 0, stream>>>(feats, in_idx, out_idx, mask, W_in, h);
    conv2_mfma<<<grid, 256, 0, stream>>>(h, in_idx, out_idx, mask, W_out, out);
}